// Round 7
// baseline (131.595 us; speedup 1.0000x reference)
//
#include <hip/hip_runtime.h>

#define BB 2
#define NN 1000
#define NC 81
#define CC 80
#define SCORE_THRESH 0.05f
#define NMS_THRESH 0.5f
#define DET_PER_IMG 100

// Single fused kernel, one block per (image, class) task, ONE dispatch.
// Round-6 post-mortem: inline softmax with per-thread row reads was
// uncoalesced (64 lanes -> 64 cache lines per instr) and cost ~30 us.
// Fix: LDS-staged tiles (coalesced float4 copy), thread-per-row compute from
// LDS with bit-identical sequential numerics. Wave-ballot NMS for V<=64.
__global__ __launch_bounds__(256) void fused_nms_kernel(
    const float* __restrict__ logits,  // [B*N, 81]
    const float* __restrict__ boxreg,  // [B*N, C*4]
    const float* __restrict__ props,   // [B*N, 4]
    float* __restrict__ out) {         // [B*C, N, 5]
    __shared__ float s_sc[NN];                       // scores, persists
    __shared__ int   s_V;
    __shared__ __align__(16) float s_buf[13000];     // 52 KB, phase-aliased

    // phase>=2 carve of s_buf (stage region [0,10368) is dead by then)
    int*   s_vn   = (int*)s_buf;          // valid -> proposal idx
    float* s_vs   = s_buf + 1000;         // valid -> score
    int*   s_rank = (int*)s_buf + 2000;   // valid -> global rank
    int*   s_sn   = (int*)s_buf + 3000;   // sorted -> proposal idx
    float* s_ss   = s_buf + 4000;         // sorted -> score
    int*   s_sr   = (int*)s_buf + 5000;   // sorted -> global rank
    float* s_x1   = s_buf + 6000;
    float* s_y1   = s_buf + 7000;
    float* s_x2   = s_buf + 8000;
    float* s_y2   = s_buf + 9000;
    float* s_ar   = s_buf + 10000;
    int*   s_supp = (int*)s_buf + 11000;
    int*   s_kf   = (int*)s_buf + 12000;  // kept-order (1-based) or 0

    const int t = blockIdx.x;
    const int b = t / CC, c = t % CC;
    const int tid = threadIdx.x;
    const int rowbase = b * NN;

    // 0. zero this task's output slice (1250 float4, 16B-aligned)
    float4* outv = (float4*)(out + (size_t)t * NN * 5);
    for (int k = tid; k < NN * 5 / 4; k += 256)
        outv[k] = make_float4(0.f, 0.f, 0.f, 0.f);

    // 1. softmax scores via LDS-staged tiles. 8 tiles x 128 rows.
    // Tile flat-copy is float4-aligned: (rowbase + tile*128)*81*4 is a
    // multiple of 16 (324000*b + 41472*tile). Numeric path bit-identical to
    // the passing rounds: sequential fmax chain, sequential expf sum, 1/sum.
    {
        float* stage = s_buf;   // 10368 floats max
        for (int tile = 0; tile < 8; ++tile) {
            int r0 = tile * 128;
            int nrows = (NN - r0 < 128) ? (NN - r0) : 128;   // 128 .. 104
            int nf4 = nrows * 81 / 4;                        // 2592 / 2106
            const float4* src = (const float4*)(logits + (size_t)(rowbase + r0) * NC);
            float4* dst = (float4*)stage;
            for (int k = tid; k < nf4; k += 256) dst[k] = src[k];
            __syncthreads();
            if (tid < nrows) {
                const float* z = stage + tid * 81;   // bank (17*tid+k)%32: conflict-free
                float mx = z[0];
                for (int k = 1; k < NC; k++) mx = fmaxf(mx, z[k]);
                float sum = 0.f;
                for (int k = 0; k < NC; k++) sum += expf(z[k] - mx);
                float inv = 1.f / sum;
                s_sc[r0 + tid] = expf(z[c + 1] - mx) * inv;
            }
            __syncthreads();
        }
    }
    if (tid == 0) s_V = 0;
    __syncthreads();

    // 2. compact valid set (score > thresh)
    for (int n = tid; n < NN; n += 256) {
        float s = s_sc[n];
        if (s > SCORE_THRESH) {
            int i = atomicAdd(&s_V, 1);
            s_vn[i] = n;
            s_vs[i] = s;
        }
    }
    __syncthreads();
    const int V = s_V;

    // 3. global rank of each valid item among all 1000 (stable argsort pos)
    for (int i = tid; i < V; i += 256) s_rank[i] = 0;
    __syncthreads();
    for (int n = tid; n < NN; n += 256) {
        float sn = s_sc[n];
        for (int i = 0; i < V; i++) {
            float sv = s_vs[i];
            if (sn > sv || (sn == sv && n < s_vn[i])) atomicAdd(&s_rank[i], 1);
        }
    }
    __syncthreads();

    // 4. order valid items by rank (ranks distinct via stable tiebreak)
    for (int i = tid; i < V; i += 256) {
        int r = s_rank[i];
        int p = 0;
        for (int u = 0; u < V; u++) p += (s_rank[u] < r) ? 1 : 0;
        s_sn[p] = s_vn[i];
        s_ss[p] = s_vs[i];
        s_sr[p] = r;
    }
    __syncthreads();

    // 5. decode boxes only for the valid items
    for (int p = tid; p < V; p += 256) {
        int n = s_sn[p];
        int row = rowbase + n;
        float p0 = props[row * 4 + 0], p1 = props[row * 4 + 1];
        float p2 = props[row * 4 + 2], p3 = props[row * 4 + 3];
        float px = (p0 + p2) * 0.5f, py = (p1 + p3) * 0.5f;
        float pw = p2 - p0, ph = p3 - p1;
        const float* rg = boxreg + (size_t)row * (CC * 4) + c * 4;
        float gx = rg[0] * pw + px;
        float gy = rg[1] * ph + py;
        float gw = pw * expf(rg[2]);
        float gh = ph * expf(rg[3]);
        float x1 = gx - gw * 0.5f, y1 = gy - gh * 0.5f;
        float x2 = gx + gw * 0.5f, y2 = gy + gh * 0.5f;
        s_x1[p] = x1; s_y1[p] = y1; s_x2[p] = x2; s_y2[p] = y2;
        s_ar[p] = (x2 - x1) * (y2 - y1);
        s_supp[p] = 0;
        s_kf[p] = 0;
    }
    __syncthreads();

    // 6. greedy NMS. Fast path: whole NMS in wave 0 via 64-bit ballot when
    // V <= 64 (typical V ~ 30); no barriers inside. Fallback: the verified
    // barrier-stepped loop. Cap applies to output only, not suppression.
    if (V <= 64) {
        if (tid < 64) {
            const int lane = tid;
            const bool act = lane < V;
            float x1j = 0.f, y1j = 0.f, x2j = 0.f, y2j = 0.f, aj = 0.f;
            if (act) {
                x1j = s_x1[lane]; y1j = s_y1[lane];
                x2j = s_x2[lane]; y2j = s_y2[lane]; aj = s_ar[lane];
            }
            unsigned long long suppm = 0ull;
            int mykf = 0, kc = 0;
            for (int i = 0; i < V; ++i) {
                if ((suppm >> i) & 1ull) continue;   // uniform: ballot result
                ++kc;
                if (lane == i) mykf = kc;
                float x1i = s_x1[i], y1i = s_y1[i];    // LDS broadcast reads
                float x2i = s_x2[i], y2i = s_y2[i], ai = s_ar[i];
                float xx = fmaxf(x1i, x1j);
                float yy = fmaxf(y1i, y1j);
                float w = fmaxf(fminf(x2i, x2j) - xx, 0.f);
                float h = fmaxf(fminf(y2i, y2j) - yy, 0.f);
                float inter = w * h;
                float iou = inter / (ai + aj - inter);
                bool sup = act && (lane > i) && (iou > NMS_THRESH);
                suppm |= __ballot(sup);
            }
            if (act) s_kf[lane] = mykf;
        }
        __syncthreads();
    } else {
        int kc = 0;
        for (int i = 0; i < V; i++) {
            if (s_supp[i]) continue;   // uniform pre-barrier LDS read
            kc++;
            if (tid == 0) s_kf[i] = kc;
            float x1i = s_x1[i], y1i = s_y1[i], x2i = s_x2[i], y2i = s_y2[i];
            float ai = s_ar[i];
            for (int j = i + 1 + tid; j < V; j += 256) {
                float xx = fmaxf(x1i, s_x1[j]);
                float yy = fmaxf(y1i, s_y1[j]);
                float w = fmaxf(fminf(x2i, s_x2[j]) - xx, 0.f);
                float h = fmaxf(fminf(y2i, s_y2[j]) - yy, 0.f);
                float inter = w * h;
                float iou = inter / (ai + s_ar[j] - inter);
                if (iou > NMS_THRESH) s_supp[j] = 1;
            }
            __syncthreads();
        }
        __syncthreads();
    }

    // 7. scatter kept detections to their global-rank positions
    for (int p = tid; p < V; p += 256) {
        int kf = s_kf[p];
        if (kf > 0 && kf <= DET_PER_IMG) {
            size_t o = ((size_t)t * NN + (size_t)s_sr[p]) * 5;
            out[o + 0] = s_x1[p];
            out[o + 1] = s_y1[p];
            out[o + 2] = s_x2[p];
            out[o + 3] = s_y2[p];
            out[o + 4] = s_ss[p];
        }
    }
}

extern "C" void kernel_launch(void* const* d_in, const int* in_sizes, int n_in,
                              void* d_out, int out_size, void* d_ws, size_t ws_size,
                              hipStream_t stream) {
    const float* logits = (const float*)d_in[0];   // [B*N, 81]
    const float* boxreg = (const float*)d_in[1];   // [B*N, C*4]
    const float* props  = (const float*)d_in[2];   // [B, N, 4]
    float* out = (float*)d_out;                    // [B, C, N, 5]

    fused_nms_kernel<<<BB * CC, 256, 0, stream>>>(logits, boxreg, props, out);
}

// Round 8
// 104.503 us; speedup vs baseline: 1.2592x; 1.2592x over previous
//
#include <hip/hip_runtime.h>

#define BB 2
#define NN 1000
#define NC 81
#define CC 80
#define SCORE_THRESH 0.05f
#define NMS_THRESH 0.5f
#define DET_PER_IMG 100

// Single fused kernel, one block per (image, class) task, ONE dispatch.
// R7 post-mortem: 8x [copy|barrier|compute] with VGPR=88 exposed ~40us of
// LDS/HBM latency at 1 block/CU. R8: 4 rounds x 252 rows, launch_bounds(256,1)
// for deep load batching, and the 1000-wide rank scan deleted (valid items'
// global rank == rank within valid set, since validity is a threshold on the
// ranking score itself).
__global__ __launch_bounds__(256, 1) void fused_nms_kernel(
    const float* __restrict__ logits,  // [B*N, 81]
    const float* __restrict__ boxreg,  // [B*N, C*4]
    const float* __restrict__ props,   // [B*N, 4]
    float* __restrict__ out) {         // [B*C, N, 5]
    __shared__ float s_sc[NN];                     // scores, persists
    __shared__ int   s_V;
    __shared__ __align__(16) float s_buf[20412];   // 81.6 KB: stage / phase>=2 arrays

    // phase>=2 carve (stage region is dead after phase 1)
    int*   s_vn   = (int*)s_buf;          // valid -> proposal idx (unsorted)
    float* s_vs   = s_buf + 1000;         // valid -> score (unsorted)
    int*   s_sn   = (int*)s_buf + 2000;   // sorted -> proposal idx
    float* s_ss   = s_buf + 3000;         // sorted -> score
    float* s_x1   = s_buf + 4000;
    float* s_y1   = s_buf + 5000;
    float* s_x2   = s_buf + 6000;
    float* s_y2   = s_buf + 7000;
    float* s_ar   = s_buf + 8000;
    int*   s_supp = (int*)s_buf + 9000;
    int*   s_kf   = (int*)s_buf + 10000;  // kept-order (1-based) or 0

    const int t = blockIdx.x;
    const int b = t / CC, c = t % CC;
    const int tid = threadIdx.x;
    const int rowbase = b * NN;

    // 0. zero this task's output slice (1250 float4, 16B-aligned)
    float4* outv = (float4*)(out + (size_t)t * NN * 5);
    for (int k = tid; k < NN * 5 / 4; k += 256)
        outv[k] = make_float4(0.f, 0.f, 0.f, 0.f);

    // 1. softmax scores: 4 rounds x 252 rows (252*324 B = 16B-aligned tiles).
    // Coalesced float4 stage -> per-thread sequential stats (bit-identical
    // numeric path: fmax chain, sequential expf sum, 1/sum).
    for (int round = 0; round < 4; ++round) {
        const int r0 = round * 252;
        const int nrows = (NN - r0 < 252) ? (NN - r0) : 252;   // 252,252,252,244
        const int nf4 = nrows * 81 / 4;                        // 5103 / 4941
        const float4* src = (const float4*)(logits + (size_t)(rowbase + r0) * NC);
        float4* dst = (float4*)s_buf;
        for (int k = tid; k < nf4; k += 256) dst[k] = src[k];
        __syncthreads();
        if (tid < nrows) {
            const float* z = s_buf + tid * 81;   // bank (17*tid+k)%32: 2-way max (free)
            float mx = z[0];
            #pragma unroll
            for (int k = 1; k < NC; k++) mx = fmaxf(mx, z[k]);
            float sum = 0.f;
            #pragma unroll
            for (int k = 0; k < NC; k++) sum += expf(z[k] - mx);
            float inv = 1.f / sum;
            s_sc[r0 + tid] = expf(z[c + 1] - mx) * inv;
        }
        __syncthreads();
    }
    if (tid == 0) s_V = 0;
    __syncthreads();

    // 2. compact valid set (score > thresh)
    for (int n = tid; n < NN; n += 256) {
        float s = s_sc[n];
        if (s > SCORE_THRESH) {
            int i = atomicAdd(&s_V, 1);
            s_vn[i] = n;
            s_vs[i] = s;
        }
    }
    __syncthreads();
    const int V = s_V;

    // 3. sort valid items among themselves (score desc, index asc — the stable
    // argsort order). Global rank == within-valid rank, so scatter pos == p.
    for (int i = tid; i < V; i += 256) {
        float si = s_vs[i];
        int   ni = s_vn[i];
        int p = 0;
        for (int u = 0; u < V; u++) {
            float su = s_vs[u];
            p += (su > si || (su == si && s_vn[u] < ni)) ? 1 : 0;
        }
        s_sn[p] = ni;
        s_ss[p] = si;
    }
    __syncthreads();

    // 4. decode boxes only for the valid items
    for (int p = tid; p < V; p += 256) {
        int n = s_sn[p];
        int row = rowbase + n;
        float p0 = props[row * 4 + 0], p1 = props[row * 4 + 1];
        float p2 = props[row * 4 + 2], p3 = props[row * 4 + 3];
        float px = (p0 + p2) * 0.5f, py = (p1 + p3) * 0.5f;
        float pw = p2 - p0, ph = p3 - p1;
        const float* rg = boxreg + (size_t)row * (CC * 4) + c * 4;
        float gx = rg[0] * pw + px;
        float gy = rg[1] * ph + py;
        float gw = pw * expf(rg[2]);
        float gh = ph * expf(rg[3]);
        float x1 = gx - gw * 0.5f, y1 = gy - gh * 0.5f;
        float x2 = gx + gw * 0.5f, y2 = gy + gh * 0.5f;
        s_x1[p] = x1; s_y1[p] = y1; s_x2[p] = x2; s_y2[p] = y2;
        s_ar[p] = (x2 - x1) * (y2 - y1);
        s_supp[p] = 0;
        s_kf[p] = 0;
    }
    __syncthreads();

    // 5. greedy NMS. Wave-ballot fast path for V<=64 (typical V~30), verified
    // barrier loop as fallback. Cap applies to output only, not suppression.
    if (V <= 64) {
        if (tid < 64) {
            const int lane = tid;
            const bool act = lane < V;
            float x1j = 0.f, y1j = 0.f, x2j = 0.f, y2j = 0.f, aj = 0.f;
            if (act) {
                x1j = s_x1[lane]; y1j = s_y1[lane];
                x2j = s_x2[lane]; y2j = s_y2[lane]; aj = s_ar[lane];
            }
            unsigned long long suppm = 0ull;
            int mykf = 0, kc = 0;
            for (int i = 0; i < V; ++i) {
                if ((suppm >> i) & 1ull) continue;   // uniform: ballot result
                ++kc;
                if (lane == i) mykf = kc;
                float x1i = s_x1[i], y1i = s_y1[i];  // LDS broadcast reads
                float x2i = s_x2[i], y2i = s_y2[i], ai = s_ar[i];
                float xx = fmaxf(x1i, x1j);
                float yy = fmaxf(y1i, y1j);
                float w = fmaxf(fminf(x2i, x2j) - xx, 0.f);
                float h = fmaxf(fminf(y2i, y2j) - yy, 0.f);
                float inter = w * h;
                float iou = inter / (ai + aj - inter);
                bool sup = act && (lane > i) && (iou > NMS_THRESH);
                suppm |= __ballot(sup);
            }
            if (act) s_kf[lane] = mykf;
        }
        __syncthreads();
    } else {
        int kc = 0;
        for (int i = 0; i < V; i++) {
            if (s_supp[i]) continue;   // uniform pre-barrier LDS read
            kc++;
            if (tid == 0) s_kf[i] = kc;
            float x1i = s_x1[i], y1i = s_y1[i], x2i = s_x2[i], y2i = s_y2[i];
            float ai = s_ar[i];
            for (int j = i + 1 + tid; j < V; j += 256) {
                float xx = fmaxf(x1i, s_x1[j]);
                float yy = fmaxf(y1i, s_y1[j]);
                float w = fmaxf(fminf(x2i, s_x2[j]) - xx, 0.f);
                float h = fmaxf(fminf(y2i, s_y2[j]) - yy, 0.f);
                float inter = w * h;
                float iou = inter / (ai + s_ar[j] - inter);
                if (iou > NMS_THRESH) s_supp[j] = 1;
            }
            __syncthreads();
        }
        __syncthreads();
    }

    // 6. scatter kept detections to their sorted positions
    for (int p = tid; p < V; p += 256) {
        int kf = s_kf[p];
        if (kf > 0 && kf <= DET_PER_IMG) {
            size_t o = ((size_t)t * NN + (size_t)p) * 5;
            out[o + 0] = s_x1[p];
            out[o + 1] = s_y1[p];
            out[o + 2] = s_x2[p];
            out[o + 3] = s_y2[p];
            out[o + 4] = s_ss[p];
        }
    }
}

extern "C" void kernel_launch(void* const* d_in, const int* in_sizes, int n_in,
                              void* d_out, int out_size, void* d_ws, size_t ws_size,
                              hipStream_t stream) {
    const float* logits = (const float*)d_in[0];   // [B*N, 81]
    const float* boxreg = (const float*)d_in[1];   // [B*N, C*4]
    const float* props  = (const float*)d_in[2];   // [B, N, 4]
    float* out = (float*)d_out;                    // [B, C, N, 5]

    fused_nms_kernel<<<BB * CC, 256, 0, stream>>>(logits, boxreg, props, out);
}

// Round 9
// 82.492 us; speedup vs baseline: 1.5952x; 1.2668x over previous
//
#include <hip/hip_runtime.h>

#define BB 2
#define NN 1000
#define NC 81
#define CC 80
#define SCORE_THRESH 0.05f
#define NMS_THRESH 0.5f
#define DET_PER_IMG 100

// MEASUREMENT ROUND: split fused kernel into K1 (softmax+transpose) and
// K2 (per-task NMS) so rocprof's per-dispatch dur_us localizes the ~50us
// of unexplained stall that survived R6->R8 restructurings.

// K1: 16 blocks x 128 rows. Coalesced stage -> sequential row stats
// (bit-exact vs all passing rounds) -> transposed [B,C,N] score write.
__global__ __launch_bounds__(256) void softmax_transpose_kernel(
    const float* __restrict__ logits,   // [B*N, 81]
    float* __restrict__ sc) {           // [B*C, N]
    __shared__ __align__(16) float stage[128 * 81];   // 41472 B
    __shared__ float s_mx[128], s_inv[128];
    const int tid = threadIdx.x;
    const int r0 = blockIdx.x * 128;
    const int nr = (BB * NN - r0 < 128) ? (BB * NN - r0) : 128;  // 128 or 80

    // coalesced float4 copy (r0*81*4 B is a multiple of 16: 128*81*4=41472)
    const float4* src = (const float4*)(logits + (size_t)r0 * NC);
    float4* dst = (float4*)stage;
    const int nf4 = nr * NC / 4;   // 2592 or 1620
    for (int k = tid; k < nf4; k += 256) dst[k] = src[k];
    __syncthreads();

    // per-row stats, sequential numeric path (absmax 0.0 anchor)
    if (tid < nr) {
        const float* z = stage + tid * NC;
        float mx = z[0];
        #pragma unroll
        for (int k = 1; k < NC; k++) mx = fmaxf(mx, z[k]);
        float sum = 0.f;
        #pragma unroll
        for (int k = 0; k < NC; k++) sum += expf(z[k] - mx);
        s_mx[tid] = mx;
        s_inv[tid] = 1.f / sum;
    }
    __syncthreads();

    // transposed write: for fixed c, consecutive lanes hit consecutive n
    for (int idx = tid; idx < CC * 128; idx += 256) {
        int c = idx >> 7, i = idx & 127;
        if (i < nr) {
            int r = r0 + i;
            int b = r / NN, n = r - b * NN;
            sc[((size_t)(b * CC + c)) * NN + n] =
                expf(stage[i * NC + c + 1] - s_mx[i]) * s_inv[i];
        }
    }
}

// K2: one block per (image, class) task. Contiguous score-slice read,
// compact -> V-internal sort -> decode -> ballot NMS -> zero+scatter.
__global__ __launch_bounds__(256) void nms_task_kernel(
    const float* __restrict__ sc,      // [B*C, N]
    const float* __restrict__ boxreg,  // [B*N, C*4]
    const float* __restrict__ props,   // [B*N, 4]
    float* __restrict__ out) {         // [B*C, N, 5]
    __shared__ __align__(16) float s_sc[NN];
    __shared__ float s_vs[NN];
    __shared__ int   s_vn[NN];
    __shared__ int   s_sn[NN];
    __shared__ float s_ss[NN];
    __shared__ float s_x1[NN], s_y1[NN], s_x2[NN], s_y2[NN], s_ar[NN];
    __shared__ int   s_supp[NN];
    __shared__ int   s_kf[NN];
    __shared__ int   s_V;

    const int t = blockIdx.x;
    const int b = t / CC, c = t % CC;
    const int tid = threadIdx.x;
    const int rowbase = b * NN;

    // zero this task's output slice (1250 float4, 16B-aligned)
    float4* outv = (float4*)(out + (size_t)t * NN * 5);
    for (int k = tid; k < NN * 5 / 4; k += 256)
        outv[k] = make_float4(0.f, 0.f, 0.f, 0.f);

    // contiguous 4 KB score-slice load
    {
        const float4* s4 = (const float4*)(sc + (size_t)t * NN);
        float4* d4 = (float4*)s_sc;
        for (int k = tid; k < NN / 4; k += 256) d4[k] = s4[k];
    }
    if (tid == 0) s_V = 0;
    __syncthreads();

    // compact valid set (score > thresh)
    for (int n = tid; n < NN; n += 256) {
        float s = s_sc[n];
        if (s > SCORE_THRESH) {
            int i = atomicAdd(&s_V, 1);
            s_vn[i] = n;
            s_vs[i] = s;
        }
    }
    __syncthreads();
    const int V = s_V;

    // sort valid items among themselves (global rank == within-valid rank,
    // since validity is a threshold on the ranking score itself)
    for (int i = tid; i < V; i += 256) {
        float si = s_vs[i];
        int   ni = s_vn[i];
        int p = 0;
        for (int u = 0; u < V; u++) {
            float su = s_vs[u];
            p += (su > si || (su == si && s_vn[u] < ni)) ? 1 : 0;
        }
        s_sn[p] = ni;
        s_ss[p] = si;
    }
    __syncthreads();

    // decode boxes for the valid items only
    for (int p = tid; p < V; p += 256) {
        int n = s_sn[p];
        int row = rowbase + n;
        float p0 = props[row * 4 + 0], p1 = props[row * 4 + 1];
        float p2 = props[row * 4 + 2], p3 = props[row * 4 + 3];
        float px = (p0 + p2) * 0.5f, py = (p1 + p3) * 0.5f;
        float pw = p2 - p0, ph = p3 - p1;
        const float* rg = boxreg + (size_t)row * (CC * 4) + c * 4;
        float gx = rg[0] * pw + px;
        float gy = rg[1] * ph + py;
        float gw = pw * expf(rg[2]);
        float gh = ph * expf(rg[3]);
        float x1 = gx - gw * 0.5f, y1 = gy - gh * 0.5f;
        float x2 = gx + gw * 0.5f, y2 = gy + gh * 0.5f;
        s_x1[p] = x1; s_y1[p] = y1; s_x2[p] = x2; s_y2[p] = y2;
        s_ar[p] = (x2 - x1) * (y2 - y1);
        s_supp[p] = 0;
        s_kf[p] = 0;
    }
    __syncthreads();

    // greedy NMS: ballot fast path (V<=64, typical ~30), barrier fallback
    if (V <= 64) {
        if (tid < 64) {
            const int lane = tid;
            const bool act = lane < V;
            float x1j = 0.f, y1j = 0.f, x2j = 0.f, y2j = 0.f, aj = 0.f;
            if (act) {
                x1j = s_x1[lane]; y1j = s_y1[lane];
                x2j = s_x2[lane]; y2j = s_y2[lane]; aj = s_ar[lane];
            }
            unsigned long long suppm = 0ull;
            int mykf = 0, kc = 0;
            for (int i = 0; i < V; ++i) {
                if ((suppm >> i) & 1ull) continue;
                ++kc;
                if (lane == i) mykf = kc;
                float x1i = s_x1[i], y1i = s_y1[i];
                float x2i = s_x2[i], y2i = s_y2[i], ai = s_ar[i];
                float xx = fmaxf(x1i, x1j);
                float yy = fmaxf(y1i, y1j);
                float w = fmaxf(fminf(x2i, x2j) - xx, 0.f);
                float h = fmaxf(fminf(y2i, y2j) - yy, 0.f);
                float inter = w * h;
                float iou = inter / (ai + aj - inter);
                bool sup = act && (lane > i) && (iou > NMS_THRESH);
                suppm |= __ballot(sup);
            }
            if (act) s_kf[lane] = mykf;
        }
        __syncthreads();
    } else {
        int kc = 0;
        for (int i = 0; i < V; i++) {
            if (s_supp[i]) continue;
            kc++;
            if (tid == 0) s_kf[i] = kc;
            float x1i = s_x1[i], y1i = s_y1[i], x2i = s_x2[i], y2i = s_y2[i];
            float ai = s_ar[i];
            for (int j = i + 1 + tid; j < V; j += 256) {
                float xx = fmaxf(x1i, s_x1[j]);
                float yy = fmaxf(y1i, s_y1[j]);
                float w = fmaxf(fminf(x2i, s_x2[j]) - xx, 0.f);
                float h = fmaxf(fminf(y2i, s_y2[j]) - yy, 0.f);
                float inter = w * h;
                float iou = inter / (ai + s_ar[j] - inter);
                if (iou > NMS_THRESH) s_supp[j] = 1;
            }
            __syncthreads();
        }
        __syncthreads();
    }

    // scatter kept detections to their sorted positions
    for (int p = tid; p < V; p += 256) {
        int kf = s_kf[p];
        if (kf > 0 && kf <= DET_PER_IMG) {
            size_t o = ((size_t)t * NN + (size_t)p) * 5;
            out[o + 0] = s_x1[p];
            out[o + 1] = s_y1[p];
            out[o + 2] = s_x2[p];
            out[o + 3] = s_y2[p];
            out[o + 4] = s_ss[p];
        }
    }
}

extern "C" void kernel_launch(void* const* d_in, const int* in_sizes, int n_in,
                              void* d_out, int out_size, void* d_ws, size_t ws_size,
                              hipStream_t stream) {
    const float* logits = (const float*)d_in[0];   // [B*N, 81]
    const float* boxreg = (const float*)d_in[1];   // [B*N, C*4]
    const float* props  = (const float*)d_in[2];   // [B, N, 4]
    float* out = (float*)d_out;                    // [B, C, N, 5]
    float* sc  = (float*)d_ws;                     // [B*C, N] scores (640 KB)

    softmax_transpose_kernel<<<(BB * NN + 127) / 128, 256, 0, stream>>>(logits, sc);
    nms_task_kernel<<<BB * CC, 256, 0, stream>>>(sc, boxreg, props, out);
}